// Round 6
// baseline (496.911 us; speedup 1.0000x reference)
//
#include <hip/hip_runtime.h>

#define Bq 8
#define Tq 64
#define Sq 256
#define Hq 768
#define GPB 32          // workgroups per batch (scan)
#define NSTEP 64
#define NSLOT 256       // per-(b,t) Z partial slots = GPB * 8 waves

typedef float f32x4 __attribute__((ext_vector_type(4)));
typedef __bf16 bf16x8 __attribute__((ext_vector_type(8)));

#define TANH_SCALE 2.885390081777927f   // 2*log2(e)
#define LOG2E 1.4426950408889634f
#define POISON 0xFFFFFFFFu

// ---------------- projection GEMMs (bf16 MFMA, direct-from-global frags) -----
// Also: grid-stride poisons Zpart and zeroes lacc (runs before scan in-stream).
__global__ __launch_bounds__(256) void proj_kernel(
    const float* __restrict__ enc, const float* __restrict__ dec,
    const float* __restrict__ Wh, const float* __restrict__ Wd,
    const float* __restrict__ bd,
    float* __restrict__ ef, float* __restrict__ decf,
    unsigned* __restrict__ Zpart, float* __restrict__ lacc)
{
  // side duty: poison Z slots + zero loss accumulator
  {
    const int total = Bq * NSTEP * NSLOT;                 // 131072
    int idx = blockIdx.x * 256 + threadIdx.x;
    for (int i = idx; i < total; i += gridDim.x * 256) Zpart[i] = POISON;
    if (idx == 0) lacc[0] = 0.f;
  }

  const int NT = Hq / 64;                       // 12 n-tiles
  int bid = blockIdx.x;
  const int efBlocks = (Bq * Sq / 64) * NT;     // 384
  const float* A; const float* W; float* C; bool hasBias;
  if (bid < efBlocks) { A = enc; W = Wh; C = ef; hasBias = false; }
  else { bid -= efBlocks; A = dec; W = Wd; C = decf; hasBias = true; }
  int bm = bid / NT, bn = bid % NT;
  int w = threadIdx.x >> 6, ln = threadIdx.x & 63;
  int m0 = bm * 64 + (w >> 1) * 32;
  int n0 = bn * 64 + (w & 1) * 32;
  int rsel = ln & 15;
  int kof = (ln >> 4) * 8;
  f32x4 acc[2][2] = {};
  for (int k0 = 0; k0 < Hq; k0 += 32) {
    bf16x8 af[2], bfr[2];
#pragma unroll
    for (int tm = 0; tm < 2; tm++) {
      const float* p = A + (size_t)(m0 + tm * 16 + rsel) * Hq + k0 + kof;
      f32x4 lo = *(const f32x4*)p, hi = *(const f32x4*)(p + 4);
      bf16x8 t;
      t[0] = (__bf16)lo[0]; t[1] = (__bf16)lo[1]; t[2] = (__bf16)lo[2]; t[3] = (__bf16)lo[3];
      t[4] = (__bf16)hi[0]; t[5] = (__bf16)hi[1]; t[6] = (__bf16)hi[2]; t[7] = (__bf16)hi[3];
      af[tm] = t;
    }
#pragma unroll
    for (int tn = 0; tn < 2; tn++) {
      const float* p = W + (size_t)(n0 + tn * 16 + rsel) * Hq + k0 + kof;
      f32x4 lo = *(const f32x4*)p, hi = *(const f32x4*)(p + 4);
      bf16x8 t;
      t[0] = (__bf16)lo[0]; t[1] = (__bf16)lo[1]; t[2] = (__bf16)lo[2]; t[3] = (__bf16)lo[3];
      t[4] = (__bf16)hi[0]; t[5] = (__bf16)hi[1]; t[6] = (__bf16)hi[2]; t[7] = (__bf16)hi[3];
      bfr[tn] = t;
    }
#pragma unroll
    for (int tm = 0; tm < 2; tm++)
#pragma unroll
      for (int tn = 0; tn < 2; tn++)
        acc[tm][tn] = __builtin_amdgcn_mfma_f32_16x16x32_bf16(af[tm], bfr[tn], acc[tm][tn], 0, 0, 0);
  }
  int col = ln & 15, rb = (ln >> 4) * 4;
#pragma unroll
  for (int tm = 0; tm < 2; tm++)
#pragma unroll
    for (int tn = 0; tn < 2; tn++)
#pragma unroll
      for (int j = 0; j < 4; j++) {
        int r = m0 + tm * 16 + rb + j, c = n0 + tn * 16 + col;
        float val = acc[tm][tn][j];
        if (hasBias) val += bd[c];
        C[(size_t)r * Hq + c] = val * TANH_SCALE;
      }
}

// ---------------- persistent scan kernel -------------------------------------
// 256 blocks x 512 threads. b = bid&7, g = bid>>3 (0..31). Wave w owns row
// s0 = g*8 + w (1 row per wave, 12 elems/lane). Per step each wave stores its
// E directly to an agent-scope slot (no LDS gather hop); wave0 is the sole
// poller of the 256 slots and broadcasts Z via write-once zshs[t] in LDS.
__global__ __launch_bounds__(512, 1) void scan_kernel(
    const float* __restrict__ ef, const float* __restrict__ decf,
    const float* __restrict__ emask, const float* __restrict__ cov0,
    const float* __restrict__ vvec, const float* __restrict__ wcvec,
    const float* __restrict__ dmask,
    float* __restrict__ out_attn, float* __restrict__ out_covf,
    unsigned* __restrict__ Zpart, float* __restrict__ lacc)
{
  __shared__ unsigned zshs[NSTEP];
  __shared__ float lossb[8];
  const int b = blockIdx.x & 7;
  const int g = blockIdx.x >> 3;
  const int w = threadIdx.x >> 6;
  const int ln = threadIdx.x & 63;
  const int tid = threadIdx.x;
  const int s0 = g * 8 + w;
  const int hb = 4 * ln;

  if (tid < NSTEP) zshs[tid] = POISON;
  __syncthreads();

  f32x4 vv[3], wcv[3], ef0[3];
  const float* efr0 = ef + (size_t)(b * Sq + s0) * Hq;
#pragma unroll
  for (int jj = 0; jj < 3; jj++) {
    int o = hb + 256 * jj;
    vv[jj]  = *(const f32x4*)(vvec + o);
    f32x4 wcl = *(const f32x4*)(wcvec + o);
    wcv[jj] = wcl * TANH_SCALE;
    ef0[jj] = *(const f32x4*)(efr0 + o);
  }
  float cva = cov0[b * Sq + s0];
  const float em0 = emask[b * Sq + s0];
  const float dm = dmask[b * Tq + ln];   // lane t holds dmask[b][t]
  float lp = 0.f;

  f32x4 dv[3];
#pragma unroll
  for (int jj = 0; jj < 3; jj++)
    dv[jj] = *(const f32x4*)(decf + (size_t)(b * Tq) * Hq + hb + 256 * jj);

  for (int t = 0; t < NSTEP; t++) {
    float acc0 = 0.f;
#pragma unroll
    for (int jj = 0; jj < 3; jj++)
#pragma unroll
      for (int e = 0; e < 4; e++) {
        float xa = ef0[jj][e] + dv[jj][e] + cva * wcv[jj][e];  // pre-scaled
        float ta = 1.f - 2.f * __builtin_amdgcn_rcpf(1.f + __builtin_amdgcn_exp2f(xa));
        acc0 += vv[jj][e] * ta;
      }
#pragma unroll
    for (int off = 32; off; off >>= 1) acc0 += __shfl_xor(acc0, off);
    float E0 = __builtin_amdgcn_exp2f(acc0 * LOG2E) * em0;

    const int base = (b * NSTEP + t) * NSLOT;
    if (ln == 0)        // direct per-wave store: no LDS gather hop
      __hip_atomic_store(&Zpart[base + g * 8 + w], __float_as_uint(E0),
                         __ATOMIC_RELAXED, __HIP_MEMORY_SCOPE_AGENT);

    // issue next decf prefetch; stays in flight across the Z wait
    f32x4 dvn[3];
    if (t + 1 < NSTEP) {
      const float* drn = decf + (size_t)(b * Tq + t + 1) * Hq;
#pragma unroll
      for (int jj = 0; jj < 3; jj++) dvn[jj] = *(const f32x4*)(drn + hb + 256 * jj);
    }

    float zf;
    if (w == 0) {
      const unsigned* Zs = Zpart + base + 4 * ln;   // lane covers 4 slots
      unsigned u0, u1, u2, u3;
      do {
        u0 = __hip_atomic_load(Zs + 0, __ATOMIC_RELAXED, __HIP_MEMORY_SCOPE_AGENT);
        u1 = __hip_atomic_load(Zs + 1, __ATOMIC_RELAXED, __HIP_MEMORY_SCOPE_AGENT);
        u2 = __hip_atomic_load(Zs + 2, __ATOMIC_RELAXED, __HIP_MEMORY_SCOPE_AGENT);
        u3 = __hip_atomic_load(Zs + 3, __ATOMIC_RELAXED, __HIP_MEMORY_SCOPE_AGENT);
      } while (__ballot((u0 == POISON) | (u1 == POISON) |
                        (u2 == POISON) | (u3 == POISON)));
      zf = __uint_as_float(u0) + __uint_as_float(u1) +
           __uint_as_float(u2) + __uint_as_float(u3);
#pragma unroll
      for (int off = 32; off; off >>= 1) zf += __shfl_xor(zf, off);
      if (ln == 0)
        __hip_atomic_store(&zshs[t], __float_as_uint(zf),
                           __ATOMIC_RELEASE, __HIP_MEMORY_SCOPE_WORKGROUP);
    } else {
      unsigned u;
      do {
        u = __hip_atomic_load(&zshs[t],
                              __ATOMIC_ACQUIRE, __HIP_MEMORY_SCOPE_WORKGROUP);
      } while (u == POISON);
      zf = __uint_as_float(u);
    }

    const float invZ = __builtin_amdgcn_rcpf(zf);
    float at0 = E0 * invZ;
    lp += fminf(at0, cva) * __shfl(dm, t);
    cva += at0;
    if (ln == 0)
      out_attn[(size_t)(b * Tq + t) * Sq + s0] = at0;
#pragma unroll
    for (int jj = 0; jj < 3; jj++) dv[jj] = dvn[jj];
  }

  if (ln == 0) {
    out_covf[b * Sq + s0] = cva;
    lossb[w] = lp;
  }
  __syncthreads();
  if (w == 0) {
    float p = (ln < 8) ? lossb[ln] : 0.f;
    p += __shfl_xor(p, 1); p += __shfl_xor(p, 2); p += __shfl_xor(p, 4);
    if (ln == 0) atomicAdd(lacc, p);
  }
}

// ---------------- deferred ht = attn @ enc (fp32 VALU) + loss finalize -------
// grid 96: (b, tc of 16 t-rows(4), hc of 256 h-cols(3)). 256 threads.
__global__ __launch_bounds__(256) void ht_kernel(
    const float* __restrict__ attn, const float* __restrict__ enc,
    const float* __restrict__ dmask, const float* __restrict__ lacc,
    float* __restrict__ out_ht, float* __restrict__ out_loss)
{
  __shared__ float lat[16][Sq];
  __shared__ float r4[4];
  int bid = blockIdx.x;
  int b = bid / 12, r = bid % 12, tc = r / 3, hc = r % 3;
  int tid = threadIdx.x;
  int h = hc * 256 + tid;
#pragma unroll
  for (int tt = 0; tt < 16; tt++)
    lat[tt][tid] = attn[(size_t)(b * Tq + tc * 16 + tt) * Sq + tid];
  __syncthreads();
  float acc[16] = {};
  for (int s = 0; s < Sq; s++) {
    float e = enc[(size_t)(b * Sq + s) * Hq + h];
#pragma unroll
    for (int tt = 0; tt < 16; tt++) acc[tt] += lat[tt][s] * e;
  }
#pragma unroll
  for (int tt = 0; tt < 16; tt++)
    out_ht[(size_t)(b * Tq + tc * 16 + tt) * Hq + h] = acc[tt];

  if (blockIdx.x == 0) {
    float s = 0.f;
    for (int i = tid; i < Bq * Tq; i += 256) s += dmask[i];
#pragma unroll
    for (int off = 32; off; off >>= 1) s += __shfl_xor(s, off);
    int w = tid >> 6, ln = tid & 63;
    if (ln == 0) r4[w] = s;
    __syncthreads();
    if (tid == 0) out_loss[0] = lacc[0] / (r4[0] + r4[1] + r4[2] + r4[3]);
  }
}

extern "C" void kernel_launch(void* const* d_in, const int* in_sizes, int n_in,
                              void* d_out, int out_size, void* d_ws, size_t ws_size,
                              hipStream_t stream) {
  const float* dec   = (const float*)d_in[0];   // [8,64,768]
  const float* dmask = (const float*)d_in[1];   // [8,64]
  const float* enc   = (const float*)d_in[2];   // [8,256,768]
  const float* emask = (const float*)d_in[3];   // [8,256]
  const float* cov0  = (const float*)d_in[4];   // [8,256]
  const float* Wh    = (const float*)d_in[5];   // [768,768]
  const float* Wd    = (const float*)d_in[6];   // [768,768]
  const float* bd    = (const float*)d_in[7];   // [768]
  const float* wc    = (const float*)d_in[8];   // [768]
  const float* vv    = (const float*)d_in[9];   // [768]
  float* out = (float*)d_out;

  char* ws = (char*)d_ws;
  float*    ef    = (float*)ws;                   // 2048*768 f32 = 6291456 B
  float*    decf  = (float*)(ws + 6291456);       // 512*768 f32 = 1572864 B
  unsigned* Zpart = (unsigned*)(ws + 7864320);    // 8*64*256 u32 = 524288 B
  float*    lacc  = (float*)(ws + 8388608);       // 1 f32

  const size_t OFF_ATTN = (size_t)Bq * Tq * Hq;             // 393216
  const size_t OFF_LOSS = OFF_ATTN + (size_t)Bq * Tq * Sq;  // 524288
  const size_t OFF_COV  = OFF_LOSS + 1;                     // 524289

  proj_kernel<<<480, 256, 0, stream>>>(enc, dec, Wh, Wd, bd, ef, decf,
                                       Zpart, lacc);
  scan_kernel<<<Bq * GPB, 512, 0, stream>>>(ef, decf, emask, cov0, vv, wc,
                                            dmask, out + OFF_ATTN,
                                            out + OFF_COV, Zpart, lacc);
  ht_kernel<<<96, 256, 0, stream>>>(out + OFF_ATTN, enc, dmask, lacc,
                                    out, out + OFF_LOSS);
}

// Round 7
// 226.071 us; speedup vs baseline: 2.1980x; 2.1980x over previous
//
#include <hip/hip_runtime.h>

#define Bq 8
#define Tq 64
#define Sq 256
#define Hq 768
#define GPB 16          // workgroups per batch (scan)
#define NSTEP 64

typedef float f32x4 __attribute__((ext_vector_type(4)));
typedef __bf16 bf16x8 __attribute__((ext_vector_type(8)));

#define TANH_SCALE 2.885390081777927f   // 2*log2(e)
#define LOG2E 1.4426950408889634f
#define POISON 0xFFFFFFFFu
#define ZMASK 0xFFFFFFFFFFFFFULL        // low 52 bits: fixed-point Z sum

// ---------------- projection GEMMs (bf16 MFMA, direct-from-global frags) -----
// Side duty: zero the Zsync words + loss accumulator (stream-ordered pre-scan).
__global__ __launch_bounds__(256) void proj_kernel(
    const float* __restrict__ enc, const float* __restrict__ dec,
    const float* __restrict__ Wh, const float* __restrict__ Wd,
    const float* __restrict__ bd,
    float* __restrict__ ef, float* __restrict__ decf,
    unsigned long long* __restrict__ Zsync, float* __restrict__ lacc)
{
  {
    int idx = blockIdx.x * 256 + threadIdx.x;
    if (idx < Bq * NSTEP * 8) Zsync[idx] = 0ULL;   // 4096 words (64B stride/(b,t))
    if (idx == 0) lacc[0] = 0.f;
  }

  const int NT = Hq / 64;                       // 12 n-tiles
  int bid = blockIdx.x;
  const int efBlocks = (Bq * Sq / 64) * NT;     // 384
  const float* A; const float* W; float* C; bool hasBias;
  if (bid < efBlocks) { A = enc; W = Wh; C = ef; hasBias = false; }
  else { bid -= efBlocks; A = dec; W = Wd; C = decf; hasBias = true; }
  int bm = bid / NT, bn = bid % NT;
  int w = threadIdx.x >> 6, ln = threadIdx.x & 63;
  int m0 = bm * 64 + (w >> 1) * 32;
  int n0 = bn * 64 + (w & 1) * 32;
  int rsel = ln & 15;
  int kof = (ln >> 4) * 8;
  f32x4 acc[2][2] = {};
  for (int k0 = 0; k0 < Hq; k0 += 32) {
    bf16x8 af[2], bfr[2];
#pragma unroll
    for (int tm = 0; tm < 2; tm++) {
      const float* p = A + (size_t)(m0 + tm * 16 + rsel) * Hq + k0 + kof;
      f32x4 lo = *(const f32x4*)p, hi = *(const f32x4*)(p + 4);
      bf16x8 t;
      t[0] = (__bf16)lo[0]; t[1] = (__bf16)lo[1]; t[2] = (__bf16)lo[2]; t[3] = (__bf16)lo[3];
      t[4] = (__bf16)hi[0]; t[5] = (__bf16)hi[1]; t[6] = (__bf16)hi[2]; t[7] = (__bf16)hi[3];
      af[tm] = t;
    }
#pragma unroll
    for (int tn = 0; tn < 2; tn++) {
      const float* p = W + (size_t)(n0 + tn * 16 + rsel) * Hq + k0 + kof;
      f32x4 lo = *(const f32x4*)p, hi = *(const f32x4*)(p + 4);
      bf16x8 t;
      t[0] = (__bf16)lo[0]; t[1] = (__bf16)lo[1]; t[2] = (__bf16)lo[2]; t[3] = (__bf16)lo[3];
      t[4] = (__bf16)hi[0]; t[5] = (__bf16)hi[1]; t[6] = (__bf16)hi[2]; t[7] = (__bf16)hi[3];
      bfr[tn] = t;
    }
#pragma unroll
    for (int tm = 0; tm < 2; tm++)
#pragma unroll
      for (int tn = 0; tn < 2; tn++)
        acc[tm][tn] = __builtin_amdgcn_mfma_f32_16x16x32_bf16(af[tm], bfr[tn], acc[tm][tn], 0, 0, 0);
  }
  int col = ln & 15, rb = (ln >> 4) * 4;
#pragma unroll
  for (int tm = 0; tm < 2; tm++)
#pragma unroll
    for (int tn = 0; tn < 2; tn++)
#pragma unroll
      for (int j = 0; j < 4; j++) {
        int r = m0 + tm * 16 + rb + j, c = n0 + tn * 16 + col;
        float val = acc[tm][tn][j];
        if (hasBias) val += bd[c];
        C[(size_t)r * Hq + c] = val * TANH_SCALE;
      }
}

// ---------------- persistent scan kernel -------------------------------------
// 128 blocks x 512 threads. b = bid&7, g = bid>>3. Wave w owns s0=g*16+2w, s1.
// No __syncthreads in the T-loop (LDS release/acquire flags as round 5).
// Cross-WG sync per step: ONE packed u64 atomicAdd per WG
//   word += (1<<52) | (partial * 1024)
// Poller (wave0 only) spins on the single word until count==GPB; value and
// readiness arrive in the same load. 64B stride between (b,t) words.
__global__ __launch_bounds__(512, 1) void scan_kernel(
    const float* __restrict__ ef, const float* __restrict__ decf,
    const float* __restrict__ emask, const float* __restrict__ cov0,
    const float* __restrict__ vvec, const float* __restrict__ wcvec,
    const float* __restrict__ dmask,
    float* __restrict__ out_attn, float* __restrict__ out_covf,
    unsigned long long* __restrict__ Zsync, float* __restrict__ lacc)
{
  __shared__ unsigned zsum[2][8];
  __shared__ unsigned zshs[NSTEP];
  __shared__ float lossb[8];
  const int b = blockIdx.x & 7;
  const int g = blockIdx.x >> 3;
  const int w = threadIdx.x >> 6;
  const int ln = threadIdx.x & 63;
  const int tid = threadIdx.x;
  const int s0 = g * 16 + w * 2, s1 = s0 + 1;
  const int hb = 4 * ln;

  if (tid < NSTEP) zshs[tid] = POISON;
  if (tid < 16) ((unsigned*)zsum)[tid] = POISON;
  __syncthreads();

  f32x4 vv[3], wcv[3], ef0[3], ef1[3];
  const float* efr0 = ef + (size_t)(b * Sq + s0) * Hq;
  const float* efr1 = ef + (size_t)(b * Sq + s1) * Hq;
#pragma unroll
  for (int jj = 0; jj < 3; jj++) {
    int o = hb + 256 * jj;
    vv[jj]  = *(const f32x4*)(vvec + o);
    f32x4 wcl = *(const f32x4*)(wcvec + o);
    wcv[jj] = wcl * TANH_SCALE;
    ef0[jj] = *(const f32x4*)(efr0 + o);
    ef1[jj] = *(const f32x4*)(efr1 + o);
  }
  float cva = cov0[b * Sq + s0], cvb = cov0[b * Sq + s1];
  const float em0 = emask[b * Sq + s0], em1 = emask[b * Sq + s1];
  const float dm = dmask[b * Tq + ln];   // lane t holds dmask[b][t]
  float lp = 0.f;

  f32x4 dv[3];
#pragma unroll
  for (int jj = 0; jj < 3; jj++)
    dv[jj] = *(const f32x4*)(decf + (size_t)(b * Tq) * Hq + hb + 256 * jj);

  for (int t = 0; t < NSTEP; t++) {
    const int par = t & 1;
    float acc0 = 0.f, acc1 = 0.f;
#pragma unroll
    for (int jj = 0; jj < 3; jj++)
#pragma unroll
      for (int e = 0; e < 4; e++) {
        float d = dv[jj][e], wcx = wcv[jj][e], vx = vv[jj][e];
        float xa = ef0[jj][e] + d + cva * wcx;    // pre-scaled by 2*log2(e)
        float xb = ef1[jj][e] + d + cvb * wcx;
        float ta = 1.f - 2.f * __builtin_amdgcn_rcpf(1.f + __builtin_amdgcn_exp2f(xa));
        float tb = 1.f - 2.f * __builtin_amdgcn_rcpf(1.f + __builtin_amdgcn_exp2f(xb));
        acc0 += vx * ta;
        acc1 += vx * tb;
      }
#pragma unroll
    for (int off = 32; off; off >>= 1) {
      acc0 += __shfl_xor(acc0, off);
      acc1 += __shfl_xor(acc1, off);
    }
    float E0 = __builtin_amdgcn_exp2f(acc0 * LOG2E) * em0;
    float E1 = __builtin_amdgcn_exp2f(acc1 * LOG2E) * em1;
    if (ln == 0)
      __hip_atomic_store(&zsum[par][w], __float_as_uint(E0 + E1),
                         __ATOMIC_RELEASE, __HIP_MEMORY_SCOPE_WORKGROUP);

    // issue next decf prefetch; stays in flight across the Z wait
    f32x4 dvn[3];
    if (t + 1 < NSTEP) {
      const float* drn = decf + (size_t)(b * Tq + t + 1) * Hq;
#pragma unroll
      for (int jj = 0; jj < 3; jj++) dvn[jj] = *(const f32x4*)(drn + hb + 256 * jj);
    }

    const int widx = (b * NSTEP + t) * 8;       // 64B stride between words
    float zf;
    if (w == 0) {
      // gather 8 wave partials from LDS (spin)
      unsigned zu;
      do {
        zu = __hip_atomic_load(&zsum[par][ln & 7],
                               __ATOMIC_ACQUIRE, __HIP_MEMORY_SCOPE_WORKGROUP);
      } while (__ballot(zu == POISON));
      float p = (ln < 8) ? __uint_as_float(zu) : 0.f;
      p += __shfl_xor(p, 1); p += __shfl_xor(p, 2); p += __shfl_xor(p, 4);
      if (ln == 0) {
        unsigned long long pkt =
            (1ULL << 52) | (unsigned long long)(p * 1024.0f);
        atomicAdd(&Zsync[widx], pkt);
      }
      // single-word poll: count nibble + value in one load
      unsigned long long v;
      do {
        v = __hip_atomic_load(&Zsync[widx],
                              __ATOMIC_RELAXED, __HIP_MEMORY_SCOPE_AGENT);
      } while ((unsigned)(v >> 52) != GPB);
      zf = (float)(v & ZMASK) * (1.0f / 1024.0f);
      if (ln < 8)
        __hip_atomic_store(&zsum[par][ln], POISON,
                           __ATOMIC_RELAXED, __HIP_MEMORY_SCOPE_WORKGROUP);
      if (ln == 0)
        __hip_atomic_store(&zshs[t], __float_as_uint(zf),
                           __ATOMIC_RELEASE, __HIP_MEMORY_SCOPE_WORKGROUP);
    } else {
      unsigned u;
      do {
        u = __hip_atomic_load(&zshs[t],
                              __ATOMIC_ACQUIRE, __HIP_MEMORY_SCOPE_WORKGROUP);
      } while (u == POISON);
      zf = __uint_as_float(u);
    }

    const float invZ = __builtin_amdgcn_rcpf(zf);
    float at0 = E0 * invZ, at1 = E1 * invZ;
    lp += (fminf(at0, cva) + fminf(at1, cvb)) * __shfl(dm, t);
    cva += at0; cvb += at1;
    if (ln == 0) {
      out_attn[(size_t)(b * Tq + t) * Sq + s0] = at0;
      out_attn[(size_t)(b * Tq + t) * Sq + s1] = at1;
    }
#pragma unroll
    for (int jj = 0; jj < 3; jj++) dv[jj] = dvn[jj];
  }

  if (ln == 0) {
    out_covf[b * Sq + s0] = cva;
    out_covf[b * Sq + s1] = cvb;
    lossb[w] = lp;
  }
  __syncthreads();
  if (w == 0) {
    float p = (ln < 8) ? lossb[ln] : 0.f;
    p += __shfl_xor(p, 1); p += __shfl_xor(p, 2); p += __shfl_xor(p, 4);
    if (ln == 0) atomicAdd(lacc, p);
  }
}

// ---------------- deferred ht = attn @ enc (fp32 VALU) + loss finalize -------
// grid 96: (b, tc of 16 t-rows(4), hc of 256 h-cols(3)). 256 threads.
__global__ __launch_bounds__(256) void ht_kernel(
    const float* __restrict__ attn, const float* __restrict__ enc,
    const float* __restrict__ dmask, const float* __restrict__ lacc,
    float* __restrict__ out_ht, float* __restrict__ out_loss)
{
  __shared__ float lat[16][Sq];
  __shared__ float r4[4];
  int bid = blockIdx.x;
  int b = bid / 12, r = bid % 12, tc = r / 3, hc = r % 3;
  int tid = threadIdx.x;
  int h = hc * 256 + tid;
#pragma unroll
  for (int tt = 0; tt < 16; tt++)
    lat[tt][tid] = attn[(size_t)(b * Tq + tc * 16 + tt) * Sq + tid];
  __syncthreads();
  float acc[16] = {};
  for (int s = 0; s < Sq; s++) {
    float e = enc[(size_t)(b * Sq + s) * Hq + h];
#pragma unroll
    for (int tt = 0; tt < 16; tt++) acc[tt] += lat[tt][s] * e;
  }
#pragma unroll
  for (int tt = 0; tt < 16; tt++)
    out_ht[(size_t)(b * Tq + tc * 16 + tt) * Hq + h] = acc[tt];

  if (blockIdx.x == 0) {
    float s = 0.f;
    for (int i = tid; i < Bq * Tq; i += 256) s += dmask[i];
#pragma unroll
    for (int off = 32; off; off >>= 1) s += __shfl_xor(s, off);
    int w = tid >> 6, ln = tid & 63;
    if (ln == 0) r4[w] = s;
    __syncthreads();
    if (tid == 0) out_loss[0] = lacc[0] / (r4[0] + r4[1] + r4[2] + r4[3]);
  }
}

extern "C" void kernel_launch(void* const* d_in, const int* in_sizes, int n_in,
                              void* d_out, int out_size, void* d_ws, size_t ws_size,
                              hipStream_t stream) {
  const float* dec   = (const float*)d_in[0];   // [8,64,768]
  const float* dmask = (const float*)d_in[1];   // [8,64]
  const float* enc   = (const float*)d_in[2];   // [8,256,768]
  const float* emask = (const float*)d_in[3];   // [8,256]
  const float* cov0  = (const float*)d_in[4];   // [8,256]
  const float* Wh    = (const float*)d_in[5];   // [768,768]
  const float* Wd    = (const float*)d_in[6];   // [768,768]
  const float* bd    = (const float*)d_in[7];   // [768]
  const float* wc    = (const float*)d_in[8];   // [768]
  const float* vv    = (const float*)d_in[9];   // [768]
  float* out = (float*)d_out;

  char* ws = (char*)d_ws;
  float* ef   = (float*)ws;                           // 6291456 B
  float* decf = (float*)(ws + 6291456);               // 1572864 B
  unsigned long long* Zsync = (unsigned long long*)(ws + 7864320); // 32768 B
  float* lacc = (float*)(ws + 7897088);               // 4 B

  const size_t OFF_ATTN = (size_t)Bq * Tq * Hq;             // 393216
  const size_t OFF_LOSS = OFF_ATTN + (size_t)Bq * Tq * Sq;  // 524288
  const size_t OFF_COV  = OFF_LOSS + 1;                     // 524289

  proj_kernel<<<480, 256, 0, stream>>>(enc, dec, Wh, Wd, bd, ef, decf,
                                       Zsync, lacc);
  scan_kernel<<<Bq * GPB, 512, 0, stream>>>(ef, decf, emask, cov0, vv, wc,
                                            dmask, out + OFF_ATTN,
                                            out + OFF_COV, Zsync, lacc);
  ht_kernel<<<96, 256, 0, stream>>>(out + OFF_ATTN, enc, dmask, lacc,
                                    out, out + OFF_LOSS);
}

// Round 9
// 215.245 us; speedup vs baseline: 2.3086x; 1.0503x over previous
//
#include <hip/hip_runtime.h>

#define Bq 8
#define Tq 64
#define Sq 256
#define Hq 768
#define GPB 16          // workgroups per batch (scan)
#define NSTEP 64

typedef float f32x4 __attribute__((ext_vector_type(4)));
typedef __bf16 bf16x8 __attribute__((ext_vector_type(8)));

#define TANH_SCALE 2.885390081777927f   // 2*log2(e)
#define LOG2E 1.4426950408889634f
#define POISON 0xFFFFFFFFu
#define ZMASK 0xFFFFFFFFFFFFFULL        // low 52 bits: fixed-point Z sum

// ---- DPP reduction helpers (VALU-pipe; ctrl/rmask must be literal consts) ---
template <int Ctrl, int Rmask>
__device__ __forceinline__ float dpp_add_f(float v) {
  int t = __builtin_amdgcn_update_dpp(0, __float_as_int(v), Ctrl, Rmask, 0xF, true);
  return v + __int_as_float(t);
}
// full 64-lane sum, result broadcast to all lanes via readlane(63)
__device__ __forceinline__ float wave64_sum(float v) {
  v = dpp_add_f<0xB1, 0xF>(v);    // quad_perm [1,0,3,2]  : xor1
  v = dpp_add_f<0x4E, 0xF>(v);    // quad_perm [2,3,0,1]  : xor2
  v = dpp_add_f<0x141, 0xF>(v);   // row_half_mirror      : xor4
  v = dpp_add_f<0x140, 0xF>(v);   // row_mirror           : xor8
  v = dpp_add_f<0x142, 0xA>(v);   // row_bcast15 -> rows 1,3
  v = dpp_add_f<0x143, 0xC>(v);   // row_bcast31 -> rows 2,3 ; lane63 = total
  return __int_as_float(__builtin_amdgcn_readlane(__float_as_int(v), 63));
}
// sum within each 16-lane row (rows replicate 16 values -> every lane = total)
__device__ __forceinline__ float row16_sum(float v) {
  v = dpp_add_f<0xB1, 0xF>(v);
  v = dpp_add_f<0x4E, 0xF>(v);
  v = dpp_add_f<0x141, 0xF>(v);
  v = dpp_add_f<0x140, 0xF>(v);
  return v;
}

// ---------------- projection GEMMs (bf16 MFMA, direct-from-global frags) -----
// Side duty: zero the Zsync words + loss accumulator (stream-ordered pre-scan).
__global__ __launch_bounds__(256) void proj_kernel(
    const float* __restrict__ enc, const float* __restrict__ dec,
    const float* __restrict__ Wh, const float* __restrict__ Wd,
    const float* __restrict__ bd,
    float* __restrict__ ef, float* __restrict__ decf,
    unsigned long long* __restrict__ Zsync, float* __restrict__ lacc)
{
  {
    int idx = blockIdx.x * 256 + threadIdx.x;
    if (idx < Bq * NSTEP * 8) Zsync[idx] = 0ULL;   // 64B stride per (b,t) word
    if (idx == 0) lacc[0] = 0.f;
  }

  const int NT = Hq / 64;                       // 12 n-tiles
  int bid = blockIdx.x;
  const int efBlocks = (Bq * Sq / 64) * NT;     // 384
  const float* A; const float* W; float* C; bool hasBias;
  if (bid < efBlocks) { A = enc; W = Wh; C = ef; hasBias = false; }
  else { bid -= efBlocks; A = dec; W = Wd; C = decf; hasBias = true; }
  int bm = bid / NT, bn = bid % NT;
  int w = threadIdx.x >> 6, ln = threadIdx.x & 63;
  int m0 = bm * 64 + (w >> 1) * 32;
  int n0 = bn * 64 + (w & 1) * 32;
  int rsel = ln & 15;
  int kof = (ln >> 4) * 8;
  f32x4 acc[2][2] = {};
  for (int k0 = 0; k0 < Hq; k0 += 32) {
    bf16x8 af[2], bfr[2];
#pragma unroll
    for (int tm = 0; tm < 2; tm++) {
      const float* p = A + (size_t)(m0 + tm * 16 + rsel) * Hq + k0 + kof;
      f32x4 lo = *(const f32x4*)p, hi = *(const f32x4*)(p + 4);
      bf16x8 t;
      t[0] = (__bf16)lo[0]; t[1] = (__bf16)lo[1]; t[2] = (__bf16)lo[2]; t[3] = (__bf16)lo[3];
      t[4] = (__bf16)hi[0]; t[5] = (__bf16)hi[1]; t[6] = (__bf16)hi[2]; t[7] = (__bf16)hi[3];
      af[tm] = t;
    }
#pragma unroll
    for (int tn = 0; tn < 2; tn++) {
      const float* p = W + (size_t)(n0 + tn * 16 + rsel) * Hq + k0 + kof;
      f32x4 lo = *(const f32x4*)p, hi = *(const f32x4*)(p + 4);
      bf16x8 t;
      t[0] = (__bf16)lo[0]; t[1] = (__bf16)lo[1]; t[2] = (__bf16)lo[2]; t[3] = (__bf16)lo[3];
      t[4] = (__bf16)hi[0]; t[5] = (__bf16)hi[1]; t[6] = (__bf16)hi[2]; t[7] = (__bf16)hi[3];
      bfr[tn] = t;
    }
#pragma unroll
    for (int tm = 0; tm < 2; tm++)
#pragma unroll
      for (int tn = 0; tn < 2; tn++)
        acc[tm][tn] = __builtin_amdgcn_mfma_f32_16x16x32_bf16(af[tm], bfr[tn], acc[tm][tn], 0, 0, 0);
  }
  int col = ln & 15, rb = (ln >> 4) * 4;
#pragma unroll
  for (int tm = 0; tm < 2; tm++)
#pragma unroll
    for (int tn = 0; tn < 2; tn++)
#pragma unroll
      for (int j = 0; j < 4; j++) {
        int r = m0 + tm * 16 + rb + j, c = n0 + tn * 16 + col;
        float val = acc[tm][tn][j];
        if (hasBias) val += bd[c];
        C[(size_t)r * Hq + c] = val * TANH_SCALE;
      }
}

// ---------------- persistent scan kernel -------------------------------------
// 128 blocks x 1024 threads (16 waves). b = bid&7, g = bid>>3. Wave w owns
// row s0 = g*16 + w (12 elems/lane). Reductions via DPP (VALU pipe).
// Cross-WG per step: ONE packed u64 atomicAdd per WG, wave0 sole poller with
// a 2-deep pipelined poll; LDS relay (all relaxed atomics) inside the WG.
__global__ __launch_bounds__(1024, 1) void scan_kernel(
    const float* __restrict__ ef, const float* __restrict__ decf,
    const float* __restrict__ emask, const float* __restrict__ cov0,
    const float* __restrict__ vvec, const float* __restrict__ wcvec,
    const float* __restrict__ dmask,
    float* __restrict__ out_attn, float* __restrict__ out_covf,
    unsigned long long* __restrict__ Zsync, float* __restrict__ lacc)
{
  __shared__ unsigned zsum[2][16];
  __shared__ unsigned zshs[NSTEP];
  __shared__ float lossb[16];
  const int b = blockIdx.x & 7;
  const int g = blockIdx.x >> 3;
  const int w = threadIdx.x >> 6;        // 0..15
  const int ln = threadIdx.x & 63;
  const int tid = threadIdx.x;
  const int s0 = g * 16 + w;
  const int hb = 4 * ln;

  if (tid < NSTEP) zshs[tid] = POISON;
  if (tid < 32) ((unsigned*)zsum)[tid] = POISON;
  __syncthreads();

  f32x4 vv[3], wcv[3], ef0[3];
  const float* efr0 = ef + (size_t)(b * Sq + s0) * Hq;
#pragma unroll
  for (int jj = 0; jj < 3; jj++) {
    int o = hb + 256 * jj;
    vv[jj]  = *(const f32x4*)(vvec + o);
    f32x4 wcl = *(const f32x4*)(wcvec + o);
    wcv[jj] = wcl * TANH_SCALE;
    ef0[jj] = *(const f32x4*)(efr0 + o);
  }
  float cva = cov0[b * Sq + s0];
  const float em0 = emask[b * Sq + s0];
  const float dm = dmask[b * Tq + ln];   // lane t holds dmask[b][t]
  float lp = 0.f;

  f32x4 dv[3];
#pragma unroll
  for (int jj = 0; jj < 3; jj++)
    dv[jj] = *(const f32x4*)(decf + (size_t)(b * Tq) * Hq + hb + 256 * jj);

  for (int t = 0; t < NSTEP; t++) {
    const int par = t & 1;
    float acc0 = 0.f;
#pragma unroll
    for (int jj = 0; jj < 3; jj++)
#pragma unroll
      for (int e = 0; e < 4; e++) {
        float xa = ef0[jj][e] + dv[jj][e] + cva * wcv[jj][e];  // pre-scaled
        float ta = 1.f - 2.f * __builtin_amdgcn_rcpf(1.f + __builtin_amdgcn_exp2f(xa));
        acc0 += vv[jj][e] * ta;
      }
    float tot = wave64_sum(acc0);                 // DPP, ~20cyc
    float E0 = __builtin_amdgcn_exp2f(tot * LOG2E) * em0;
    if (ln == 0)
      __hip_atomic_store(&zsum[par][w], __float_as_uint(E0),
                         __ATOMIC_RELAXED, __HIP_MEMORY_SCOPE_WORKGROUP);

    // issue next decf prefetch; stays in flight across the Z wait
    f32x4 dvn[3];
    if (t + 1 < NSTEP) {
      const float* drn = decf + (size_t)(b * Tq + t + 1) * Hq;
#pragma unroll
      for (int jj = 0; jj < 3; jj++) dvn[jj] = *(const f32x4*)(drn + hb + 256 * jj);
    }

    const int widx = (b * NSTEP + t) * 8;         // 64B stride between words
    float zf;
    if (w == 0) {
      // gather 16 wave partials from LDS (lanes replicate slots -> DPP sum)
      unsigned zu;
      do {
        zu = __hip_atomic_load(&zsum[par][ln & 15],
                               __ATOMIC_RELAXED, __HIP_MEMORY_SCOPE_WORKGROUP);
      } while (__ballot(zu == POISON));
      float p = row16_sum(__uint_as_float(zu));   // all lanes hold WG partial
      if (ln == 0) {
        unsigned long long pkt =
            (1ULL << 52) | (unsigned long long)(p * 1024.0f);
        atomicAdd(&Zsync[widx], pkt);
      }
      // 2-deep pipelined poll: two outstanding loads, checked alternately
      const unsigned long long* Wp = &Zsync[widx];
      unsigned long long v0 = __hip_atomic_load(Wp, __ATOMIC_RELAXED, __HIP_MEMORY_SCOPE_AGENT);
      unsigned long long v1 = __hip_atomic_load(Wp, __ATOMIC_RELAXED, __HIP_MEMORY_SCOPE_AGENT);
      unsigned long long vf;
      for (;;) {
        if ((unsigned)(v0 >> 52) == GPB) { vf = v0; break; }
        v0 = __hip_atomic_load(Wp, __ATOMIC_RELAXED, __HIP_MEMORY_SCOPE_AGENT);
        if ((unsigned)(v1 >> 52) == GPB) { vf = v1; break; }
        v1 = __hip_atomic_load(Wp, __ATOMIC_RELAXED, __HIP_MEMORY_SCOPE_AGENT);
      }
      zf = (float)(vf & ZMASK) * (1.0f / 1024.0f);
      if (ln < 16)
        __hip_atomic_store(&zsum[par][ln], POISON,
                           __ATOMIC_RELAXED, __HIP_MEMORY_SCOPE_WORKGROUP);
      if (ln == 0)
        __hip_atomic_store(&zshs[t], __float_as_uint(zf),
                           __ATOMIC_RELAXED, __HIP_MEMORY_SCOPE_WORKGROUP);
    } else {
      unsigned u;
      do {
        u = __hip_atomic_load(&zshs[t],
                              __ATOMIC_RELAXED, __HIP_MEMORY_SCOPE_WORKGROUP);
      } while (u == POISON);
      zf = __uint_as_float(u);
    }

    const float invZ = __builtin_amdgcn_rcpf(zf);
    float at0 = E0 * invZ;
    lp += fminf(at0, cva) * __shfl(dm, t);
    cva += at0;
    if (ln == 0)
      out_attn[(size_t)(b * Tq + t) * Sq + s0] = at0;
#pragma unroll
    for (int jj = 0; jj < 3; jj++) dv[jj] = dvn[jj];
  }

  if (ln == 0) {
    out_covf[b * Sq + s0] = cva;
    lossb[w] = lp;
  }
  __syncthreads();
  if (w == 0) {
    float p = (ln < 16) ? lossb[ln] : 0.f;
    p += __shfl_xor(p, 1); p += __shfl_xor(p, 2);
    p += __shfl_xor(p, 4); p += __shfl_xor(p, 8);
    if (ln == 0) atomicAdd(lacc, p);
  }
}

// ---------------- deferred ht = attn @ enc (fp32 VALU) + loss finalize -------
// grid 96: (b, tc of 16 t-rows(4), hc of 256 h-cols(3)). 256 threads.
__global__ __launch_bounds__(256) void ht_kernel(
    const float* __restrict__ attn, const float* __restrict__ enc,
    const float* __restrict__ dmask, const float* __restrict__ lacc,
    float* __restrict__ out_ht, float* __restrict__ out_loss)
{
  __shared__ float lat[16][Sq];
  __shared__ float r4[4];
  int bid = blockIdx.x;
  int b = bid / 12, r = bid % 12, tc = r / 3, hc = r % 3;
  int tid = threadIdx.x;
  int h = hc * 256 + tid;
#pragma unroll
  for (int tt = 0; tt < 16; tt++)
    lat[tt][tid] = attn[(size_t)(b * Tq + tc * 16 + tt) * Sq + tid];
  __syncthreads();
  float acc[16] = {};
  for (int s = 0; s < Sq; s++) {
    float e = enc[(size_t)(b * Sq + s) * Hq + h];
#pragma unroll
    for (int tt = 0; tt < 16; tt++) acc[tt] += lat[tt][s] * e;
  }
#pragma unroll
  for (int tt = 0; tt < 16; tt++)
    out_ht[(size_t)(b * Tq + tc * 16 + tt) * Hq + h] = acc[tt];

  if (blockIdx.x == 0) {
    float s = 0.f;
    for (int i = tid; i < Bq * Tq; i += 256) s += dmask[i];
#pragma unroll
    for (int off = 32; off; off >>= 1) s += __shfl_xor(s, off);
    int w = tid >> 6, ln = tid & 63;
    if (ln == 0) r4[w] = s;
    __syncthreads();
    if (tid == 0) out_loss[0] = lacc[0] / (r4[0] + r4[1] + r4[2] + r4[3]);
  }
}

extern "C" void kernel_launch(void* const* d_in, const int* in_sizes, int n_in,
                              void* d_out, int out_size, void* d_ws, size_t ws_size,
                              hipStream_t stream) {
  const float* dec   = (const float*)d_in[0];   // [8,64,768]
  const float* dmask = (const float*)d_in[1];   // [8,64]
  const float* enc   = (const float*)d_in[2];   // [8,256,768]
  const float* emask = (const float*)d_in[3];   // [8,256]
  const float* cov0  = (const float*)d_in[4];   // [8,256]
  const float* Wh    = (const float*)d_in[5];   // [768,768]
  const float* Wd    = (const float*)d_in[6];   // [768,768]
  const float* bd    = (const float*)d_in[7];   // [768]
  const float* wc    = (const float*)d_in[8];   // [768]
  const float* vv    = (const float*)d_in[9];   // [768]
  float* out = (float*)d_out;

  char* ws = (char*)d_ws;
  float* ef   = (float*)ws;                           // 6291456 B
  float* decf = (float*)(ws + 6291456);               // 1572864 B
  unsigned long long* Zsync = (unsigned long long*)(ws + 7864320); // 32768 B
  float* lacc = (float*)(ws + 7897088);               // 4 B

  const size_t OFF_ATTN = (size_t)Bq * Tq * Hq;             // 393216
  const size_t OFF_LOSS = OFF_ATTN + (size_t)Bq * Tq * Sq;  // 524288
  const size_t OFF_COV  = OFF_LOSS + 1;                     // 524289

  proj_kernel<<<480, 256, 0, stream>>>(enc, dec, Wh, Wd, bd, ef, decf,
                                       Zsync, lacc);
  scan_kernel<<<Bq * GPB, 1024, 0, stream>>>(ef, decf, emask, cov0, vv, wc,
                                             dmask, out + OFF_ATTN,
                                             out + OFF_COV, Zsync, lacc);
  ht_kernel<<<96, 256, 0, stream>>>(out + OFF_ATTN, enc, dmask, lacc,
                                    out, out + OFF_LOSS);
}

// Round 10
// 189.227 us; speedup vs baseline: 2.6260x; 1.1375x over previous
//
#include <hip/hip_runtime.h>

#define Bq 8
#define Tq 64
#define Sq 256
#define Hq 768
#define GPB 16          // workgroups per batch (scan)
#define NSTEP 64

typedef float f32x4 __attribute__((ext_vector_type(4)));
typedef __bf16 bf16x8 __attribute__((ext_vector_type(8)));

#define TANH_SCALE 2.885390081777927f   // 2*log2(e)
#define LOG2E 1.4426950408889634f
#define POISON 0xFFFFFFFFu
#define ZMASK 0xFFFFFFFFFFFFFULL        // low 52 bits: fixed-point Z sum

// ---- DPP reduction helpers (VALU-pipe; ctrl/rmask must be literal consts) ---
template <int Ctrl, int Rmask>
__device__ __forceinline__ float dpp_add_f(float v) {
  int t = __builtin_amdgcn_update_dpp(0, __float_as_int(v), Ctrl, Rmask, 0xF, true);
  return v + __int_as_float(t);
}
// full 64-lane sum, result broadcast to all lanes via readlane(63)
__device__ __forceinline__ float wave64_sum(float v) {
  v = dpp_add_f<0xB1, 0xF>(v);    // quad_perm [1,0,3,2]  : xor1
  v = dpp_add_f<0x4E, 0xF>(v);    // quad_perm [2,3,0,1]  : xor2
  v = dpp_add_f<0x141, 0xF>(v);   // row_half_mirror      : xor4
  v = dpp_add_f<0x140, 0xF>(v);   // row_mirror           : xor8
  v = dpp_add_f<0x142, 0xA>(v);   // row_bcast15 -> rows 1,3
  v = dpp_add_f<0x143, 0xC>(v);   // row_bcast31 -> rows 2,3 ; lane63 = total
  return __int_as_float(__builtin_amdgcn_readlane(__float_as_int(v), 63));
}
// sum within each 16-lane row (rows replicate 16 values -> every lane = total)
__device__ __forceinline__ float row16_sum(float v) {
  v = dpp_add_f<0xB1, 0xF>(v);
  v = dpp_add_f<0x4E, 0xF>(v);
  v = dpp_add_f<0x141, 0xF>(v);
  v = dpp_add_f<0x140, 0xF>(v);
  return v;
}

// ---------------- projection GEMMs (bf16 MFMA, direct-from-global frags) -----
// Side duty: zero the Zsync words + loss accumulator (stream-ordered pre-scan).
__global__ __launch_bounds__(256) void proj_kernel(
    const float* __restrict__ enc, const float* __restrict__ dec,
    const float* __restrict__ Wh, const float* __restrict__ Wd,
    const float* __restrict__ bd,
    float* __restrict__ ef, float* __restrict__ decf,
    unsigned long long* __restrict__ Zsync, float* __restrict__ lacc)
{
  {
    int idx = blockIdx.x * 256 + threadIdx.x;
    if (idx < Bq * NSTEP * 8) Zsync[idx] = 0ULL;   // 64B stride per (b,t) word
    if (idx == 0) lacc[0] = 0.f;
  }

  const int NT = Hq / 64;                       // 12 n-tiles
  int bid = blockIdx.x;
  const int efBlocks = (Bq * Sq / 64) * NT;     // 384
  const float* A; const float* W; float* C; bool hasBias;
  if (bid < efBlocks) { A = enc; W = Wh; C = ef; hasBias = false; }
  else { bid -= efBlocks; A = dec; W = Wd; C = decf; hasBias = true; }
  int bm = bid / NT, bn = bid % NT;
  int w = threadIdx.x >> 6, ln = threadIdx.x & 63;
  int m0 = bm * 64 + (w >> 1) * 32;
  int n0 = bn * 64 + (w & 1) * 32;
  int rsel = ln & 15;
  int kof = (ln >> 4) * 8;
  f32x4 acc[2][2] = {};
  for (int k0 = 0; k0 < Hq; k0 += 32) {
    bf16x8 af[2], bfr[2];
#pragma unroll
    for (int tm = 0; tm < 2; tm++) {
      const float* p = A + (size_t)(m0 + tm * 16 + rsel) * Hq + k0 + kof;
      f32x4 lo = *(const f32x4*)p, hi = *(const f32x4*)(p + 4);
      bf16x8 t;
      t[0] = (__bf16)lo[0]; t[1] = (__bf16)lo[1]; t[2] = (__bf16)lo[2]; t[3] = (__bf16)lo[3];
      t[4] = (__bf16)hi[0]; t[5] = (__bf16)hi[1]; t[6] = (__bf16)hi[2]; t[7] = (__bf16)hi[3];
      af[tm] = t;
    }
#pragma unroll
    for (int tn = 0; tn < 2; tn++) {
      const float* p = W + (size_t)(n0 + tn * 16 + rsel) * Hq + k0 + kof;
      f32x4 lo = *(const f32x4*)p, hi = *(const f32x4*)(p + 4);
      bf16x8 t;
      t[0] = (__bf16)lo[0]; t[1] = (__bf16)lo[1]; t[2] = (__bf16)lo[2]; t[3] = (__bf16)lo[3];
      t[4] = (__bf16)hi[0]; t[5] = (__bf16)hi[1]; t[6] = (__bf16)hi[2]; t[7] = (__bf16)hi[3];
      bfr[tn] = t;
    }
#pragma unroll
    for (int tm = 0; tm < 2; tm++)
#pragma unroll
      for (int tn = 0; tn < 2; tn++)
        acc[tm][tn] = __builtin_amdgcn_mfma_f32_16x16x32_bf16(af[tm], bfr[tn], acc[tm][tn], 0, 0, 0);
  }
  int col = ln & 15, rb = (ln >> 4) * 4;
#pragma unroll
  for (int tm = 0; tm < 2; tm++)
#pragma unroll
    for (int tn = 0; tn < 2; tn++)
#pragma unroll
      for (int j = 0; j < 4; j++) {
        int r = m0 + tm * 16 + rb + j, c = n0 + tn * 16 + col;
        float val = acc[tm][tn][j];
        if (hasBias) val += bd[c];
        C[(size_t)r * Hq + c] = val * TANH_SCALE;
      }
}

// ---------------- persistent scan kernel -------------------------------------
// 128 blocks x 1024 threads (16 waves). b = bid&7, g = bid>>3. Wave w owns
// row s0 = g*16 + w (12 elems/lane). Reductions via DPP (VALU pipe).
// Cross-WG per step: ONE packed u64 atomicAdd per WG, wave0 sole poller with
// a 2-deep pipelined poll; LDS relay (all relaxed atomics) inside the WG.
// Loss terms: lane t keeps step t's fmin (NSTEP == wave size), dotted with
// dmask once after the loop (no per-step __shfl on the critical path).
__global__ __launch_bounds__(1024, 1) void scan_kernel(
    const float* __restrict__ ef, const float* __restrict__ decf,
    const float* __restrict__ emask, const float* __restrict__ cov0,
    const float* __restrict__ vvec, const float* __restrict__ wcvec,
    const float* __restrict__ dmask,
    float* __restrict__ out_attn, float* __restrict__ out_covf,
    unsigned long long* __restrict__ Zsync, float* __restrict__ lacc)
{
  __shared__ unsigned zsum[2][16];
  __shared__ unsigned zshs[NSTEP];
  __shared__ float lossb[16];
  const int b = blockIdx.x & 7;
  const int g = blockIdx.x >> 3;
  const int w = threadIdx.x >> 6;        // 0..15
  const int ln = threadIdx.x & 63;
  const int tid = threadIdx.x;
  const int s0 = g * 16 + w;
  const int hb = 4 * ln;

  if (tid < NSTEP) zshs[tid] = POISON;
  if (tid < 32) ((unsigned*)zsum)[tid] = POISON;
  __syncthreads();

  f32x4 vv[3], wcv[3], ef0[3];
  const float* efr0 = ef + (size_t)(b * Sq + s0) * Hq;
#pragma unroll
  for (int jj = 0; jj < 3; jj++) {
    int o = hb + 256 * jj;
    vv[jj]  = *(const f32x4*)(vvec + o);
    f32x4 wcl = *(const f32x4*)(wcvec + o);
    wcv[jj] = wcl * TANH_SCALE;
    ef0[jj] = *(const f32x4*)(efr0 + o);
  }
  float cva = cov0[b * Sq + s0];
  const float em0 = emask[b * Sq + s0];
  const float dm = dmask[b * Tq + ln];   // lane t holds dmask[b][t]
  float lkeep = 0.f;                     // lane t keeps step-t fmin term

  f32x4 dv[3];
#pragma unroll
  for (int jj = 0; jj < 3; jj++)
    dv[jj] = *(const f32x4*)(decf + (size_t)(b * Tq) * Hq + hb + 256 * jj);

  for (int t = 0; t < NSTEP; t++) {
    const int par = t & 1;
    float acc0 = 0.f;
#pragma unroll
    for (int jj = 0; jj < 3; jj++)
#pragma unroll
      for (int e = 0; e < 4; e++) {
        float xa = ef0[jj][e] + dv[jj][e] + cva * wcv[jj][e];  // pre-scaled
        float ta = 1.f - 2.f * __builtin_amdgcn_rcpf(1.f + __builtin_amdgcn_exp2f(xa));
        acc0 += vv[jj][e] * ta;
      }
    float tot = wave64_sum(acc0);                 // DPP, ~20cyc
    float E0 = __builtin_amdgcn_exp2f(tot * LOG2E) * em0;
    if (ln == 0)
      __hip_atomic_store(&zsum[par][w], __float_as_uint(E0),
                         __ATOMIC_RELAXED, __HIP_MEMORY_SCOPE_WORKGROUP);

    // issue next decf prefetch; stays in flight across the Z wait
    f32x4 dvn[3];
    if (t + 1 < NSTEP) {
      const float* drn = decf + (size_t)(b * Tq + t + 1) * Hq;
#pragma unroll
      for (int jj = 0; jj < 3; jj++) dvn[jj] = *(const f32x4*)(drn + hb + 256 * jj);
    }

    const int widx = (b * NSTEP + t) * 8;         // 64B stride between words
    float zf;
    if (w == 0) {
      // gather 16 wave partials from LDS (lanes replicate slots -> DPP sum)
      unsigned zu;
      do {
        zu = __hip_atomic_load(&zsum[par][ln & 15],
                               __ATOMIC_RELAXED, __HIP_MEMORY_SCOPE_WORKGROUP);
      } while (__ballot(zu == POISON));
      float p = row16_sum(__uint_as_float(zu));   // all lanes hold WG partial
      if (ln == 0) {
        unsigned long long pkt =
            (1ULL << 52) | (unsigned long long)(p * 1024.0f);
        atomicAdd(&Zsync[widx], pkt);
      }
      // 2-deep pipelined poll: two outstanding loads, checked alternately
      const unsigned long long* Wp = &Zsync[widx];
      unsigned long long v0 = __hip_atomic_load(Wp, __ATOMIC_RELAXED, __HIP_MEMORY_SCOPE_AGENT);
      unsigned long long v1 = __hip_atomic_load(Wp, __ATOMIC_RELAXED, __HIP_MEMORY_SCOPE_AGENT);
      unsigned long long vf;
      for (;;) {
        if ((unsigned)(v0 >> 52) == GPB) { vf = v0; break; }
        v0 = __hip_atomic_load(Wp, __ATOMIC_RELAXED, __HIP_MEMORY_SCOPE_AGENT);
        if ((unsigned)(v1 >> 52) == GPB) { vf = v1; break; }
        v1 = __hip_atomic_load(Wp, __ATOMIC_RELAXED, __HIP_MEMORY_SCOPE_AGENT);
      }
      zf = (float)(vf & ZMASK) * (1.0f / 1024.0f);
      if (ln < 16)
        __hip_atomic_store(&zsum[par][ln], POISON,
                           __ATOMIC_RELAXED, __HIP_MEMORY_SCOPE_WORKGROUP);
      if (ln == 0)
        __hip_atomic_store(&zshs[t], __float_as_uint(zf),
                           __ATOMIC_RELAXED, __HIP_MEMORY_SCOPE_WORKGROUP);
    } else {
      unsigned u;
      do {
        u = __hip_atomic_load(&zshs[t],
                              __ATOMIC_RELAXED, __HIP_MEMORY_SCOPE_WORKGROUP);
      } while (u == POISON);
      zf = __uint_as_float(u);
    }

    const float invZ = __builtin_amdgcn_rcpf(zf);
    float at0 = E0 * invZ;
    float lterm = fminf(at0, cva);
    lkeep = (ln == t) ? lterm : lkeep;   // cndmask, no cross-lane op
    cva += at0;
    if (ln == 0)
      out_attn[(size_t)(b * Tq + t) * Sq + s0] = at0;
#pragma unroll
    for (int jj = 0; jj < 3; jj++) dv[jj] = dvn[jj];
  }

  float lp = wave64_sum(lkeep * dm);     // dot with dmask once
  if (ln == 0) {
    out_covf[b * Sq + s0] = cva;
    lossb[w] = lp;
  }
  __syncthreads();
  if (w == 0) {
    float p = (ln < 16) ? lossb[ln] : 0.f;
    p += __shfl_xor(p, 1); p += __shfl_xor(p, 2);
    p += __shfl_xor(p, 4); p += __shfl_xor(p, 8);
    if (ln == 0) atomicAdd(lacc, p);
  }
}

// ---------------- deferred ht = attn @ enc (fp32 VALU) + loss finalize -------
// grid 192: (b, tc of 8 t-rows(8), hc of 256 h-cols(3)). 256 threads.
// Transposed LDS attn tile lat[s][8] (uniform-addr f32x4 broadcast reads);
// s-loop unrolled x8 with 8 independent enc loads in flight (ILP latency fix).
__global__ __launch_bounds__(256) void ht_kernel(
    const float* __restrict__ attn, const float* __restrict__ enc,
    const float* __restrict__ dmask, const float* __restrict__ lacc,
    float* __restrict__ out_ht, float* __restrict__ out_loss)
{
  __shared__ float lat[Sq][8];     // [s][tt], 8 KB
  __shared__ float r4[4];
  int bid = blockIdx.x;
  int b = bid / 24, r = bid % 24, tc = r / 3, hc = r % 3;
  int tid = threadIdx.x;
  int h = hc * 256 + tid;
#pragma unroll
  for (int tt = 0; tt < 8; tt++)
    lat[tid][tt] = attn[(size_t)(b * Tq + tc * 8 + tt) * Sq + tid];
  __syncthreads();

  float acc[8] = {};
  const float* ep = enc + (size_t)(b * Sq) * Hq + h;
  for (int sb = 0; sb < Sq; sb += 8) {
    float e[8];
#pragma unroll
    for (int u = 0; u < 8; u++) e[u] = ep[(size_t)(sb + u) * Hq];
#pragma unroll
    for (int u = 0; u < 8; u++) {
      f32x4 a0 = *(const f32x4*)&lat[sb + u][0];
      f32x4 a1 = *(const f32x4*)&lat[sb + u][4];
      acc[0] += a0[0] * e[u]; acc[1] += a0[1] * e[u];
      acc[2] += a0[2] * e[u]; acc[3] += a0[3] * e[u];
      acc[4] += a1[0] * e[u]; acc[5] += a1[1] * e[u];
      acc[6] += a1[2] * e[u]; acc[7] += a1[3] * e[u];
    }
  }
#pragma unroll
  for (int tt = 0; tt < 8; tt++)
    out_ht[(size_t)(b * Tq + tc * 8 + tt) * Hq + h] = acc[tt];

  if (blockIdx.x == 0) {
    float s = 0.f;
    for (int i = tid; i < Bq * Tq; i += 256) s += dmask[i];
#pragma unroll
    for (int off = 32; off; off >>= 1) s += __shfl_xor(s, off);
    int w = tid >> 6, ln = tid & 63;
    if (ln == 0) r4[w] = s;
    __syncthreads();
    if (tid == 0) out_loss[0] = lacc[0] / (r4[0] + r4[1] + r4[2] + r4[3]);
  }
}

extern "C" void kernel_launch(void* const* d_in, const int* in_sizes, int n_in,
                              void* d_out, int out_size, void* d_ws, size_t ws_size,
                              hipStream_t stream) {
  const float* dec   = (const float*)d_in[0];   // [8,64,768]
  const float* dmask = (const float*)d_in[1];   // [8,64]
  const float* enc   = (const float*)d_in[2];   // [8,256,768]
  const float* emask = (const float*)d_in[3];   // [8,256]
  const float* cov0  = (const float*)d_in[4];   // [8,256]
  const float* Wh    = (const float*)d_in[5];   // [768,768]
  const float* Wd    = (const float*)d_in[6];   // [768,768]
  const float* bd    = (const float*)d_in[7];   // [768]
  const float* wc    = (const float*)d_in[8];   // [768]
  const float* vv    = (const float*)d_in[9];   // [768]
  float* out = (float*)d_out;

  char* ws = (char*)d_ws;
  float* ef   = (float*)ws;                           // 6291456 B
  float* decf = (float*)(ws + 6291456);               // 1572864 B
  unsigned long long* Zsync = (unsigned long long*)(ws + 7864320); // 32768 B
  float* lacc = (float*)(ws + 7897088);               // 4 B

  const size_t OFF_ATTN = (size_t)Bq * Tq * Hq;             // 393216
  const size_t OFF_LOSS = OFF_ATTN + (size_t)Bq * Tq * Sq;  // 524288
  const size_t OFF_COV  = OFF_LOSS + 1;                     // 524289

  proj_kernel<<<480, 256, 0, stream>>>(enc, dec, Wh, Wd, bd, ef, decf,
                                       Zsync, lacc);
  scan_kernel<<<Bq * GPB, 1024, 0, stream>>>(ef, decf, emask, cov0, vv, wc,
                                             dmask, out + OFF_ATTN,
                                             out + OFF_COV, Zsync, lacc);
  ht_kernel<<<192, 256, 0, stream>>>(out + OFF_ATTN, enc, dmask, lacc,
                                     out, out + OFF_LOSS);
}